// Round 2
// baseline (46.954 us; speedup 1.0000x reference)
//
#include <hip/hip_runtime.h>

// pred/target: (32, 3, 512, 512) f32.
// V = clip(max_c(x),0,1); loss = mean |Vp - Vt| over 32*512*512 pixels.
#define HW      (512 * 512)          // per-channel plane
#define NPIX    (32 * HW)            // 8388608 pixels
#define NVEC    (NPIX / 4)           // float4-vectorized pixel count
#define NBLOCKS 2048
#define NTHREADS 256
#define NITER   (NVEC / (NBLOCKS * NTHREADS))   // = 4, exact

__device__ __forceinline__ float vmax3_clamp(float r, float g, float b) {
    float m = fmaxf(fmaxf(r, g), b);          // v_max3_f32
    return fminf(fmaxf(m, 0.0f), 1.0f);       // clip commutes with max
}

__global__ __launch_bounds__(NTHREADS) void brightness_l1_fused(
    const float* __restrict__ pred,
    const float* __restrict__ target,
    float* __restrict__ out) {
    const int tid = blockIdx.x * blockDim.x + threadIdx.x;
    const int stride = NBLOCKS * NTHREADS;

    float acc = 0.0f;
    #pragma unroll 2
    for (int k = 0; k < NITER; ++k) {
        int i  = tid + k * stride;
        int p  = i << 2;               // scalar pixel index (vec4 aligned)
        int n  = p >> 18;              // p / HW   (HW = 2^18)
        int hw = p & (HW - 1);         // p % HW
        size_t base = (size_t)n * (3 * HW) + hw;

        const float4 pr = *reinterpret_cast<const float4*>(pred + base);
        const float4 pg = *reinterpret_cast<const float4*>(pred + base + HW);
        const float4 pb = *reinterpret_cast<const float4*>(pred + base + 2 * HW);
        const float4 tr = *reinterpret_cast<const float4*>(target + base);
        const float4 tg = *reinterpret_cast<const float4*>(target + base + HW);
        const float4 tb = *reinterpret_cast<const float4*>(target + base + 2 * HW);

        acc += fabsf(vmax3_clamp(pr.x, pg.x, pb.x) - vmax3_clamp(tr.x, tg.x, tb.x));
        acc += fabsf(vmax3_clamp(pr.y, pg.y, pb.y) - vmax3_clamp(tr.y, tg.y, tb.y));
        acc += fabsf(vmax3_clamp(pr.z, pg.z, pb.z) - vmax3_clamp(tr.z, tg.z, tb.z));
        acc += fabsf(vmax3_clamp(pr.w, pg.w, pb.w) - vmax3_clamp(tr.w, tg.w, tb.w));
    }

    // wave64 tree reduce
    #pragma unroll
    for (int off = 32; off > 0; off >>= 1)
        acc += __shfl_down(acc, off, 64);

    __shared__ float smem[NTHREADS / 64];
    const int lane = threadIdx.x & 63;
    const int wave = threadIdx.x >> 6;
    if (lane == 0) smem[wave] = acc;
    __syncthreads();
    if (threadIdx.x == 0) {
        float s = smem[0];
        #pragma unroll
        for (int w = 1; w < NTHREADS / 64; ++w) s += smem[w];
        // pre-scale so the atomic accumulates the final mean directly;
        // device-scope float atomicAdd, ordering error ~1e-9 << 4.7e-3 threshold
        atomicAdd(out, s * (1.0f / (float)NPIX));
    }
}

extern "C" void kernel_launch(void* const* d_in, const int* in_sizes, int n_in,
                              void* d_out, int out_size, void* d_ws, size_t ws_size,
                              hipStream_t stream) {
    const float* pred   = (const float*)d_in[0];
    const float* target = (const float*)d_in[1];
    float* out = (float*)d_out;

    // d_out is poisoned (0xAA) before timing and not re-zeroed between replays:
    // zero it on-stream each call (graph-capturable async memset, 4 bytes).
    hipMemsetAsync(out, 0, sizeof(float), stream);
    brightness_l1_fused<<<NBLOCKS, NTHREADS, 0, stream>>>(pred, target, out);
}

// Round 3
// 38.953 us; speedup vs baseline: 1.2054x; 1.2054x over previous
//
#include <hip/hip_runtime.h>

// pred/target: (32, 3, 512, 512) f32.
// V = clip(max_c(x),0,1); loss = mean |Vp - Vt| over 32*512*512 pixels.
#define HW      (512 * 512)          // per-channel plane
#define NPIX    (32 * HW)            // 8388608 pixels
#define NVEC    (NPIX / 4)           // float4-vectorized pixel count
#define NBLOCKS 2048
#define NTHREADS 256
#define NITER   (NVEC / (NBLOCKS * NTHREADS))   // = 4, exact division

__device__ __forceinline__ float vmax3_clamp(float r, float g, float b) {
    float m = fmaxf(fmaxf(r, g), b);          // v_max3_f32
    return fminf(fmaxf(m, 0.0f), 1.0f);       // clip commutes with max
}

__global__ __launch_bounds__(NTHREADS) void brightness_l1_partial(
    const float* __restrict__ pred,
    const float* __restrict__ target,
    float* __restrict__ partials) {
    const int tid = blockIdx.x * blockDim.x + threadIdx.x;
    const int stride = NBLOCKS * NTHREADS;

    // Issue all loads first (24 independent 16B loads/thread), consume after:
    // deepens memory-level parallelism vs the 6-load rolling loop (R1, 16 VGPR).
    float4 P0[NITER], P1[NITER], P2[NITER];
    float4 T0[NITER], T1[NITER], T2[NITER];

    #pragma unroll
    for (int k = 0; k < NITER; ++k) {
        int i  = tid + k * stride;
        int p  = i << 2;               // scalar pixel index (vec4 aligned)
        int n  = p >> 18;              // p / HW   (HW = 2^18)
        int hw = p & (HW - 1);         // p % HW
        size_t base = (size_t)n * (3 * HW) + hw;
        P0[k] = *reinterpret_cast<const float4*>(pred + base);
        P1[k] = *reinterpret_cast<const float4*>(pred + base + HW);
        P2[k] = *reinterpret_cast<const float4*>(pred + base + 2 * HW);
        T0[k] = *reinterpret_cast<const float4*>(target + base);
        T1[k] = *reinterpret_cast<const float4*>(target + base + HW);
        T2[k] = *reinterpret_cast<const float4*>(target + base + 2 * HW);
    }

    float acc = 0.0f;
    #pragma unroll
    for (int k = 0; k < NITER; ++k) {
        acc += fabsf(vmax3_clamp(P0[k].x, P1[k].x, P2[k].x) - vmax3_clamp(T0[k].x, T1[k].x, T2[k].x));
        acc += fabsf(vmax3_clamp(P0[k].y, P1[k].y, P2[k].y) - vmax3_clamp(T0[k].y, T1[k].y, T2[k].y));
        acc += fabsf(vmax3_clamp(P0[k].z, P1[k].z, P2[k].z) - vmax3_clamp(T0[k].z, T1[k].z, T2[k].z));
        acc += fabsf(vmax3_clamp(P0[k].w, P1[k].w, P2[k].w) - vmax3_clamp(T0[k].w, T1[k].w, T2[k].w));
    }

    // wave64 tree reduce
    #pragma unroll
    for (int off = 32; off > 0; off >>= 1)
        acc += __shfl_down(acc, off, 64);

    __shared__ float smem[NTHREADS / 64];
    const int lane = threadIdx.x & 63;
    const int wave = threadIdx.x >> 6;
    if (lane == 0) smem[wave] = acc;
    __syncthreads();
    if (threadIdx.x == 0) {
        float s = smem[0];
        #pragma unroll
        for (int w = 1; w < NTHREADS / 64; ++w) s += smem[w];
        partials[blockIdx.x] = s;
    }
}

__global__ __launch_bounds__(NTHREADS) void brightness_l1_finalize(
    const float* __restrict__ partials,
    float* __restrict__ out) {
    float acc = 0.0f;
    for (int i = threadIdx.x; i < NBLOCKS; i += NTHREADS)
        acc += partials[i];

    #pragma unroll
    for (int off = 32; off > 0; off >>= 1)
        acc += __shfl_down(acc, off, 64);

    __shared__ float smem[NTHREADS / 64];
    const int lane = threadIdx.x & 63;
    const int wave = threadIdx.x >> 6;
    if (lane == 0) smem[wave] = acc;
    __syncthreads();
    if (threadIdx.x == 0) {
        float s = smem[0];
        #pragma unroll
        for (int w = 1; w < NTHREADS / 64; ++w) s += smem[w];
        out[0] = s * (1.0f / (float)NPIX);
    }
}

extern "C" void kernel_launch(void* const* d_in, const int* in_sizes, int n_in,
                              void* d_out, int out_size, void* d_ws, size_t ws_size,
                              hipStream_t stream) {
    const float* pred   = (const float*)d_in[0];
    const float* target = (const float*)d_in[1];
    float* out      = (float*)d_out;
    float* partials = (float*)d_ws;   // NBLOCKS floats = 8 KiB scratch

    brightness_l1_partial<<<NBLOCKS, NTHREADS, 0, stream>>>(pred, target, partials);
    brightness_l1_finalize<<<1, NTHREADS, 0, stream>>>(partials, out);
}

// Round 4
// 37.796 us; speedup vs baseline: 1.2423x; 1.0306x over previous
//
#include <hip/hip_runtime.h>

// pred/target: (32, 3, 512, 512) f32.
// V = clip(max_c(x),0,1); loss = mean |Vp - Vt| over 32*512*512 pixels.
#define HW      (512 * 512)          // per-channel plane
#define NPIX    (32 * HW)            // 8388608 pixels
#define NVEC    (NPIX / 4)           // float4-vectorized pixel count
#define NBLOCKS 2048
#define NTHREADS 256
#define NITER   (NVEC / (NBLOCKS * NTHREADS))   // = 4, exact division

typedef float f32x4 __attribute__((ext_vector_type(4)));

__device__ __forceinline__ float vmax3_clamp(float r, float g, float b) {
    float m = fmaxf(fmaxf(r, g), b);          // v_max3_f32
    return fminf(fmaxf(m, 0.0f), 1.0f);       // clip commutes with max
}

__global__ __launch_bounds__(NTHREADS) void brightness_l1_partial(
    const float* __restrict__ pred,
    const float* __restrict__ target,
    float* __restrict__ partials) {
    const int tid = blockIdx.x * blockDim.x + threadIdx.x;
    const int stride = NBLOCKS * NTHREADS;

    float acc = 0.0f;
    for (int k = 0; k < NITER; ++k) {
        int i  = tid + k * stride;
        int p  = i << 2;               // scalar pixel index (vec4 aligned)
        int n  = p >> 18;              // p / HW   (HW = 2^18)
        int hw = p & (HW - 1);         // p % HW
        size_t base = (size_t)n * (3 * HW) + hw;

        // pred: normal loads -> stays L3-resident (100.7 MB fits in 256 MB IC)
        const f32x4 pr = *reinterpret_cast<const f32x4*>(pred + base);
        const f32x4 pg = *reinterpret_cast<const f32x4*>(pred + base + HW);
        const f32x4 pb = *reinterpret_cast<const f32x4*>(pred + base + 2 * HW);
        // target: non-temporal (evict-first) -> streams from HBM, doesn't
        // thrash pred's L3 lines. Pure hint, no semantic change.
        const f32x4 tr = __builtin_nontemporal_load(reinterpret_cast<const f32x4*>(target + base));
        const f32x4 tg = __builtin_nontemporal_load(reinterpret_cast<const f32x4*>(target + base + HW));
        const f32x4 tb = __builtin_nontemporal_load(reinterpret_cast<const f32x4*>(target + base + 2 * HW));

        acc += fabsf(vmax3_clamp(pr.x, pg.x, pb.x) - vmax3_clamp(tr.x, tg.x, tb.x));
        acc += fabsf(vmax3_clamp(pr.y, pg.y, pb.y) - vmax3_clamp(tr.y, tg.y, tb.y));
        acc += fabsf(vmax3_clamp(pr.z, pg.z, pb.z) - vmax3_clamp(tr.z, tg.z, tb.z));
        acc += fabsf(vmax3_clamp(pr.w, pg.w, pb.w) - vmax3_clamp(tr.w, tg.w, tb.w));
    }

    // wave64 tree reduce
    #pragma unroll
    for (int off = 32; off > 0; off >>= 1)
        acc += __shfl_down(acc, off, 64);

    __shared__ float smem[NTHREADS / 64];
    const int lane = threadIdx.x & 63;
    const int wave = threadIdx.x >> 6;
    if (lane == 0) smem[wave] = acc;
    __syncthreads();
    if (threadIdx.x == 0) {
        float s = smem[0];
        #pragma unroll
        for (int w = 1; w < NTHREADS / 64; ++w) s += smem[w];
        partials[blockIdx.x] = s;
    }
}

__global__ __launch_bounds__(NTHREADS) void brightness_l1_finalize(
    const float* __restrict__ partials,
    float* __restrict__ out) {
    float acc = 0.0f;
    for (int i = threadIdx.x; i < NBLOCKS; i += NTHREADS)
        acc += partials[i];

    #pragma unroll
    for (int off = 32; off > 0; off >>= 1)
        acc += __shfl_down(acc, off, 64);

    __shared__ float smem[NTHREADS / 64];
    const int lane = threadIdx.x & 63;
    const int wave = threadIdx.x >> 6;
    if (lane == 0) smem[wave] = acc;
    __syncthreads();
    if (threadIdx.x == 0) {
        float s = smem[0];
        #pragma unroll
        for (int w = 1; w < NTHREADS / 64; ++w) s += smem[w];
        out[0] = s * (1.0f / (float)NPIX);
    }
}

extern "C" void kernel_launch(void* const* d_in, const int* in_sizes, int n_in,
                              void* d_out, int out_size, void* d_ws, size_t ws_size,
                              hipStream_t stream) {
    const float* pred   = (const float*)d_in[0];
    const float* target = (const float*)d_in[1];
    float* out      = (float*)d_out;
    float* partials = (float*)d_ws;   // NBLOCKS floats = 8 KiB scratch

    brightness_l1_partial<<<NBLOCKS, NTHREADS, 0, stream>>>(pred, target, partials);
    brightness_l1_finalize<<<1, NTHREADS, 0, stream>>>(partials, out);
}